// Round 10
// baseline (581.209 us; speedup 1.0000x reference)
//
#include <hip/hip_runtime.h>

// ChainMessagePassing: out[n] = sum over edges with dst==n of x[src], over two edge lists.
// x: [N=100000, 64] fp32; indices: [2, E=3200000] (src row 0, dst row 1), int64 or int32.
//
// R13: wave-uniform gather. R12 post-mortem: the gather floor (200-235us across
// 4 variants) is intra-wave DIVERGENCE - 4 independent 16-lane groups per wave
// with different trip counts serialize (VALUBusy 17.7% == 16 VALU-cyc/edge at
// 25% lane util, arithmetic matches exactly). Fix: whole wave processes ONE
// node's run; lanes = (slot 0..3) x (quad 0..15); per iteration: 1 broadcast
// ds_read (4 addrs), 1 coalesced 4x256B global load, 4 plain adds. Loop bounds
// wave-uniform (binoff) -> zero divergence; only tail lanes predicated (~28%
// slot waste at lambda=4.9 << 4x serialization). Wave owns 16 nodes, persistent
// static acc[16] (64 VGPR), slot-reduce via 2 shfl_xor at the very end.
// Tile-major sort key kept (FETCH 136-196MB verified R9/R12). Prep = R12.

static constexpr int D = 64;
static constexpr int Q = 16;          // float4 quads per row
static constexpr int NPB = 64;        // nodes per bucket
static constexpr int NPB_SHIFT = 6;
static constexpr int CHUNK = 8192;    // edges per scatter block (16/thread @512)
static constexpr int CH = 4096;       // edges per gather sort chunk (16 KB LDS)
static constexpr int MAXT = 32;       // max src tiles (nbins <= 2048)

// ---- index dtype sniffer: int64 nonneg <2^31 has all-zero odd dwords ----
__global__ void detect_idx_dtype(const int* __restrict__ w, int* __restrict__ flag) {
    int tid = threadIdx.x;  // one wave
    int v = w[2 * tid + 1];
    unsigned long long m = __ballot(v != 0);
    if (tid == 0) *flag = (m == 0ULL) ? 1 : 0;
}

__device__ __forceinline__ int load_idx_nt(const void* idx, long long i, int is64) {
    return is64 ? (int)__builtin_nontemporal_load(((const long long*)idx) + i)
                : __builtin_nontemporal_load(((const int*)idx) + i);
}

// ---- phase 1: bucket histogram, LDS-aggregated ----
__global__ __launch_bounds__(256) void bucket_hist_kernel(
        const void* __restrict__ up, const void* __restrict__ down,
        int* __restrict__ bcounts, const int* __restrict__ flag, int E, int NB) {
    extern __shared__ int lcnt[];
    const int is64 = *flag;
    for (int i = threadIdx.x; i < NB; i += blockDim.x) lcnt[i] = 0;
    __syncthreads();
    const long long total = 2LL * E;
    const long long stride = (long long)gridDim.x * blockDim.x;
    for (long long e = (long long)blockIdx.x * blockDim.x + threadIdx.x;
         e < total; e += stride) {
        const void* idx = up; long long ee = e;
        if (ee >= E) { idx = down; ee -= E; }
        int dst = load_idx_nt(idx, E + ee, is64);
        atomicAdd(&lcnt[dst >> NPB_SHIFT], 1);
    }
    __syncthreads();
    for (int i = threadIdx.x; i < NB; i += blockDim.x)
        if (lcnt[i]) atomicAdd(&bcounts[i], lcnt[i]);
}

// ---- phase 2: exclusive scan over NB buckets, one block ----
__global__ __launch_bounds__(1024) void scan_kernel(
        const int* __restrict__ counts, int* __restrict__ offsets,
        int* __restrict__ cursors, int NB) {
    __shared__ int sums[1024];
    const int tid = threadIdx.x;
    const int chunk = (NB + 1023) / 1024;
    const int start = tid * chunk;
    const int end = min(start + chunk, NB);
    int s = 0;
    for (int i = start; i < end; i++) s += counts[i];
    sums[tid] = s;
    __syncthreads();
    for (int off = 1; off < 1024; off <<= 1) {
        int t = (tid >= off) ? sums[tid - off] : 0;
        __syncthreads();
        sums[tid] += t;
        __syncthreads();
    }
    int run = (tid == 0) ? 0 : sums[tid - 1];
    for (int i = start; i < end; i++) {
        offsets[i] = run;
        cursors[i] = run;
        run += counts[i];
    }
    if (tid == 1023) offsets[NB] = run;
}

// ---- phase 3: scatter packed (src<<6 | dst&63) into bucket bins ----
// SINGLE global read pass @512 threads, CHUNK 8192: (packed,bucket) register-
// staged (16/thread), LDS histogram -> one global atomicAdd per (block,bucket)
// reserves a contiguous sub-run.
__global__ __launch_bounds__(512) void bucket_scatter_kernel(
        const void* __restrict__ up, const void* __restrict__ down,
        int* __restrict__ gcursor, unsigned* __restrict__ packed,
        const int* __restrict__ flag, int E, int NB) {
    extern __shared__ int lds[];
    int* cnt = lds;        // [NB]
    int* base = lds + NB;  // [NB]
    const int is64 = *flag;
    const long long total = 2LL * E;
    const long long cs = (long long)blockIdx.x * CHUNK;
    if (cs >= total) return;
    const int m = (int)(min(total, cs + (long long)CHUNK) - cs);
    const int tid = threadIdx.x;

    for (int i = tid; i < NB; i += 512) cnt[i] = 0;
    __syncthreads();

    unsigned pr[16];
    int bkt[16];
    #pragma unroll
    for (int k = 0; k < 16; k++) {
        const int i = tid + (k << 9);
        bkt[k] = -1;
        if (i < m) {
            long long e = cs + i;
            const void* idx = up; long long ee = e;
            if (ee >= E) { idx = down; ee -= E; }
            const int src = load_idx_nt(idx, ee, is64);
            const int dst = load_idx_nt(idx, E + ee, is64);
            pr[k] = ((unsigned)src << NPB_SHIFT) | (unsigned)(dst & (NPB - 1));
            bkt[k] = dst >> NPB_SHIFT;
            atomicAdd(&cnt[bkt[k]], 1);
        }
    }
    __syncthreads();
    for (int i = tid; i < NB; i += 512) {
        int c = cnt[i];
        base[i] = c ? atomicAdd(&gcursor[i], c) : 0;
        cnt[i] = 0;  // reuse as local cursor
    }
    __syncthreads();
    #pragma unroll
    for (int k = 0; k < 16; k++) {
        if (bkt[k] >= 0) {
            int pos = base[bkt[k]] + atomicAdd(&cnt[bkt[k]], 1);
            packed[pos] = pr[k];
        }
    }
}

// ---- phase 4: per-bucket counting sort (tile-major key) + WAVE-UNIFORM gather.
// Wave w owns nodes 16w..16w+15. Lane = (slot = lane>>4) x (q = lane&15).
// Per (tile, node): whole wave walks the run 4 edges/iter; bounds uniform ->
// no divergence; tail lanes predicated via clamp+cndmask. acc[16] persistent;
// slot-reduction (shfl_xor 16,32) once at the end. ----
__global__ __launch_bounds__(256) void bucket_gather_kernel(
        const float* __restrict__ x, const int* __restrict__ offsets,
        const unsigned* __restrict__ packed, float* __restrict__ out,
        int N, int shift, int NT) {
    extern __shared__ int lds[];
    unsigned* sorted = (unsigned*)lds;        // [CH]
    int* cnt = lds + CH;                      // [nbins] -> becomes cursor
    int* binoff = cnt + NT * NPB;             // [nbins+1]
    const int nbins = NT * NPB;

    const int b = blockIdx.x;
    const int tid = threadIdx.x;
    const int w = tid >> 6;          // wave 0..3 (owns nodes 16w..16w+15)
    const int lane = tid & 63;
    const int slot = lane >> 4;      // edge slot 0..3
    const int q = lane & 15;         // float4 quad within row
    const int beg = offsets[b], end = offsets[b + 1];
    const float* xq = x + q * 4;

    float4 acc[16];
    #pragma unroll
    for (int j = 0; j < 16; j++) acc[j] = make_float4(0.f, 0.f, 0.f, 0.f);

    for (int cs = beg; cs < end; cs += CH) {
        const int m = min(CH, end - cs);
        for (int i = tid; i < nbins; i += 256) cnt[i] = 0;
        __syncthreads();
        // hist + register stage (CH == 16*256); key = tile*NPB + dstlo
        unsigned pr[16];
        #pragma unroll
        for (int k = 0; k < 16; k++) {
            const int i = tid + (k << 8);
            if (i < m) {
                unsigned p = __builtin_nontemporal_load(packed + cs + i);
                pr[k] = p;
                int key = (int)((p >> (NPB_SHIFT + shift)) << NPB_SHIFT) | (int)(p & (NPB - 1));
                atomicAdd(&cnt[key], 1);
            }
        }
        __syncthreads();
        if (tid < 64) {  // wave 0: scan over nbins; cnt becomes exclusive cursor
            const int K = (nbins + 63) >> 6;
            const int base = tid * K;
            int S = 0;
            for (int k = 0; k < K; k++) {
                int i = base + k;
                if (i < nbins) S += cnt[i];
            }
            int inc = S;
            #pragma unroll
            for (int off = 1; off < 64; off <<= 1) {
                int t = __shfl_up(inc, off, 64);
                if (tid >= off) inc += t;
            }
            int run = inc - S;  // exclusive lane offset
            for (int k = 0; k < K; k++) {
                int i = base + k;
                if (i < nbins) {
                    int c = cnt[i];
                    cnt[i] = run;
                    binoff[i + 1] = run + c;
                    run += c;
                }
            }
            if (tid == 0) binoff[0] = 0;
        }
        __syncthreads();
        #pragma unroll
        for (int k = 0; k < 16; k++) {
            const int i = tid + (k << 8);
            if (i < m) {
                unsigned p = pr[k];
                int key = (int)((p >> (NPB_SHIFT + shift)) << NPB_SHIFT) | (int)(p & (NPB - 1));
                int pos = atomicAdd(&cnt[key], 1);
                sorted[pos] = p;
            }
        }
        __syncthreads();

        // wave-uniform accumulation: per tile, per node j (unrolled, static acc),
        // walk the run 4 edges/iteration with slot-parallel lanes.
        for (int t = 0; t < NT; t++) {
            const int kb = t * NPB + 16 * w;
            #pragma unroll
            for (int j = 0; j < 16; j++) {
                const int rb = binoff[kb + j];
                const int re = binoff[kb + j + 1];
                for (int e = rb; e < re; e += 4) {
                    const int idx = e + slot;
                    const unsigned p = sorted[min(idx, re - 1)];
                    const float4 v = *(const float4*)(xq + ((long long)(p >> NPB_SHIFT)) * D);
                    const bool act = idx < re;
                    acc[j].x += act ? v.x : 0.f;
                    acc[j].y += act ? v.y : 0.f;
                    acc[j].z += act ? v.z : 0.f;
                    acc[j].w += act ? v.w : 0.f;
                }
            }
        }
        __syncthreads();  // gather reads done before next chunk reuses LDS
    }

    // slot-reduction and store: lanes (slot,q) -> sum over slots via shfl_xor
    const int node0 = b * NPB + 16 * w;
    #pragma unroll
    for (int j = 0; j < 16; j++) {
        float4 a = acc[j];
        a.x += __shfl_xor(a.x, 16, 64); a.y += __shfl_xor(a.y, 16, 64);
        a.z += __shfl_xor(a.z, 16, 64); a.w += __shfl_xor(a.w, 16, 64);
        a.x += __shfl_xor(a.x, 32, 64); a.y += __shfl_xor(a.y, 32, 64);
        a.z += __shfl_xor(a.z, 32, 64); a.w += __shfl_xor(a.w, 32, 64);
        const int node = node0 + j;
        if (slot == 0 && node < N)
            *(float4*)(out + (long long)node * D + q * 4) = a;
    }
}

// ---- fallback: direct fp32 atomics (R1), needs no workspace ----
__global__ __launch_bounds__(256) void scatter_add_kernel(
        const float* __restrict__ x, const void* __restrict__ up_idx,
        const void* __restrict__ down_idx, float* __restrict__ out,
        const int* __restrict__ dtype_flag, int num_edges) {
    const int is64 = *dtype_flag;
    const long long total = 2LL * num_edges * Q;
    const long long stride = (long long)gridDim.x * blockDim.x;
    for (long long t = (long long)blockIdx.x * blockDim.x + threadIdx.x;
         t < total; t += stride) {
        const int quad = (int)(t & (Q - 1));
        long long eg = t >> 4;
        const void* idx = up_idx;
        if (eg >= num_edges) { idx = down_idx; eg -= num_edges; }
        int src = load_idx_nt(idx, eg, is64);
        int dst = load_idx_nt(idx, num_edges + eg, is64);
        const float4 v = *(const float4*)(x + (long long)src * D + quad * 4);
        float* o = out + (long long)dst * D + quad * 4;
        unsafeAtomicAdd(o + 0, v.x);
        unsafeAtomicAdd(o + 1, v.y);
        unsafeAtomicAdd(o + 2, v.z);
        unsafeAtomicAdd(o + 3, v.w);
    }
}

extern "C" void kernel_launch(void* const* d_in, const int* in_sizes, int n_in,
                              void* d_out, int out_size, void* d_ws, size_t ws_size,
                              hipStream_t stream) {
    const float* x = (const float*)d_in[0];
    const void* up_idx = d_in[1];
    const void* down_idx = d_in[2];
    float* out = (float*)d_out;

    const int E = in_sizes[1] / 2;   // [2, E]
    const int N = out_size / D;      // [N, 64]
    const int NB = (N + NPB - 1) / NPB;
    const long long Etot = 2LL * E;

    // src tile shift: 8192 rows (2MB) preferred; coarsen so NT <= MAXT
    int shift = 13;
    while ((((long long)(N - 1) >> shift) + 1) > MAXT) shift++;
    const int NT = (int)(((long long)(N - 1) >> shift) + 1);

    // ws layout (ints): flag(64) | counts[NB] | offsets[NB+1] pad | cursors[NB] | packed[2E]
    int* ws_i = (int*)d_ws;
    int* flag = ws_i;
    int* counts = ws_i + 64;
    int* offsets = counts + NB;
    int* cursors = offsets + NB + 15;
    unsigned* packed = (unsigned*)(cursors + NB);
    const size_t ws_need = (size_t)(64 + 3LL * NB + 16 + Etot) * 4 + 64;

    detect_idx_dtype<<<1, 64, 0, stream>>>((const int*)up_idx, flag);

    if (ws_size >= ws_need && N <= (1 << 25) && Etot < (1LL << 31)) {
        hipMemsetAsync(counts, 0, (size_t)NB * sizeof(int), stream);
        bucket_hist_kernel<<<2048, 256, NB * sizeof(int), stream>>>(
            up_idx, down_idx, counts, flag, E, NB);
        scan_kernel<<<1, 1024, 0, stream>>>(counts, offsets, cursors, NB);
        const int sblocks = (int)((Etot + CHUNK - 1) / CHUNK);
        bucket_scatter_kernel<<<sblocks, 512, 2 * NB * sizeof(int), stream>>>(
            up_idx, down_idx, cursors, packed, flag, E, NB);
        const int nbins = NT * NPB;
        const size_t glds = (size_t)(CH + 2 * nbins + 4) * 4;
        bucket_gather_kernel<<<NB, 256, glds, stream>>>(
            x, offsets, packed, out, N, shift, NT);
    } else {
        hipMemsetAsync(d_out, 0, (size_t)out_size * sizeof(float), stream);
        scatter_add_kernel<<<8192, 256, 0, stream>>>(x, up_idx, down_idx, out, flag, E);
    }
}

// Round 11
// 416.191 us; speedup vs baseline: 1.3965x; 1.3965x over previous
//
#include <hip/hip_runtime.h>

// ChainMessagePassing: out[n] = sum over edges with dst==n of x[src], over two edge lists.
// x: [N=100000, 64] fp32; indices: [2, E=3200000] (src row 0, dst row 1), int64 or int32.
//
// R14: revert gather to measured-best (R9 j-loop MLP4 accumulate + R10 single-nt-read
// register staging; 201-207us) after R12/R13 regressions (R13: wave-uniform = 1
// outstanding load/wave + 208 short-run overheads -> 340us). Attack PREP instead
// (~250us, never profiled): two-level radix scatter kills write amplification.
//  pass1: coarse bin = dst>>12 (25 bins) -> sub-runs 328 edges (1.3KB, amp ~1.0),
//         packed1 = src<<12 | dst&4095 (fast path gated N <= 2^20).
//  pass2: per coarse segment, scatter to its 64 fine buckets (sub-runs 128 edges,
//         512B, amp ~1.06) -> packed2 = src<<6 | dstlo (gather format). Chunk
//         re-reads hit L2 (32KB). Coarse-boundary spans handled explicitly.
// Falls back to proven single-pass scatter (same kernel, ks=6) if ws < 2x Etot.

static constexpr int D = 64;
static constexpr int Q = 16;          // float4 quads per row
static constexpr int NPB = 64;        // nodes per bucket
static constexpr int NPB_SHIFT = 6;
static constexpr int CSHIFT = 12;     // coarse radix: 4096 nodes/bin
static constexpr int SCHUNK = 8192;   // edges per scatter block (16/thread @512)
static constexpr int CH = 4096;       // edges per gather sort chunk (16 KB LDS)
static constexpr int MAXT = 32;       // max src tiles (nbins <= 2048)

// ---- index dtype sniffer: int64 nonneg <2^31 has all-zero odd dwords ----
__global__ void detect_idx_dtype(const int* __restrict__ w, int* __restrict__ flag) {
    int tid = threadIdx.x;  // one wave
    int v = w[2 * tid + 1];
    unsigned long long m = __ballot(v != 0);
    if (tid == 0) *flag = (m == 0ULL) ? 1 : 0;
}

__device__ __forceinline__ int load_idx_nt(const void* idx, long long i, int is64) {
    return is64 ? (int)__builtin_nontemporal_load(((const long long*)idx) + i)
                : __builtin_nontemporal_load(((const int*)idx) + i);
}

// ---- phase 1: fine bucket histogram, LDS-aggregated ----
__global__ __launch_bounds__(256) void bucket_hist_kernel(
        const void* __restrict__ up, const void* __restrict__ down,
        int* __restrict__ bcounts, const int* __restrict__ flag, int E, int NB) {
    extern __shared__ int lcnt[];
    const int is64 = *flag;
    for (int i = threadIdx.x; i < NB; i += blockDim.x) lcnt[i] = 0;
    __syncthreads();
    const long long total = 2LL * E;
    const long long stride = (long long)gridDim.x * blockDim.x;
    for (long long e = (long long)blockIdx.x * blockDim.x + threadIdx.x;
         e < total; e += stride) {
        const void* idx = up; long long ee = e;
        if (ee >= E) { idx = down; ee -= E; }
        int dst = load_idx_nt(idx, E + ee, is64);
        atomicAdd(&lcnt[dst >> NPB_SHIFT], 1);
    }
    __syncthreads();
    for (int i = threadIdx.x; i < NB; i += blockDim.x)
        if (lcnt[i]) atomicAdd(&bcounts[i], lcnt[i]);
}

// ---- phase 2: exclusive scan over NB buckets + coarse cursor init, one block ----
__global__ __launch_bounds__(1024) void scan_kernel(
        const int* __restrict__ counts, int* __restrict__ offsets,
        int* __restrict__ cursors, int* __restrict__ ccursor, int NB, int NCC) {
    __shared__ int sums[1024];
    const int tid = threadIdx.x;
    const int chunk = (NB + 1023) / 1024;
    const int start = tid * chunk;
    const int end = min(start + chunk, NB);
    int s = 0;
    for (int i = start; i < end; i++) s += counts[i];
    sums[tid] = s;
    __syncthreads();
    for (int off = 1; off < 1024; off <<= 1) {
        int t = (tid >= off) ? sums[tid - off] : 0;
        __syncthreads();
        sums[tid] += t;
        __syncthreads();
    }
    int run = (tid == 0) ? 0 : sums[tid - 1];
    for (int i = start; i < end; i++) {
        offsets[i] = run;
        cursors[i] = run;
        run += counts[i];
    }
    if (tid == 1023) offsets[NB] = run;
    __syncthreads();
    // coarse cursors: ccursor[c] = offsets[64c] (coarse bin = 64 fine buckets)
    for (int c = tid; c < NCC; c += 1024) ccursor[c] = offsets[min(c << 6, NB)];
}

// ---- phase 3a: generic radix scatter (register-staged, LDS-aggregated) ----
// bin = dst>>ks; val = src<<ks | dst&((1<<ks)-1). ks=6: single-pass fine scatter
// (R12-proven). ks=12: coarse pass of the two-level radix (25 bins, amp ~1.0).
__global__ __launch_bounds__(512) void radix_scatter_kernel(
        const void* __restrict__ up, const void* __restrict__ down,
        int* __restrict__ gcursor, unsigned* __restrict__ outbuf,
        const int* __restrict__ flag, int E, int ks, int nbins) {
    extern __shared__ int lds[];
    int* cnt = lds;           // [nbins]
    int* base = lds + nbins;  // [nbins]
    const int is64 = *flag;
    const long long total = 2LL * E;
    const long long cs = (long long)blockIdx.x * SCHUNK;
    if (cs >= total) return;
    const int m = (int)(min(total, cs + (long long)SCHUNK) - cs);
    const int tid = threadIdx.x;
    const unsigned lomask = (1u << ks) - 1u;

    for (int i = tid; i < nbins; i += 512) cnt[i] = 0;
    __syncthreads();

    unsigned pr[16];
    int bkt[16];
    #pragma unroll
    for (int k = 0; k < 16; k++) {
        const int i = tid + (k << 9);
        bkt[k] = -1;
        if (i < m) {
            long long e = cs + i;
            const void* idx = up; long long ee = e;
            if (ee >= E) { idx = down; ee -= E; }
            const int src = load_idx_nt(idx, ee, is64);
            const int dst = load_idx_nt(idx, E + ee, is64);
            pr[k] = ((unsigned)src << ks) | ((unsigned)dst & lomask);
            bkt[k] = dst >> ks;
            atomicAdd(&cnt[bkt[k]], 1);
        }
    }
    __syncthreads();
    for (int i = tid; i < nbins; i += 512) {
        int c = cnt[i];
        base[i] = c ? atomicAdd(&gcursor[i], c) : 0;
        cnt[i] = 0;  // reuse as local cursor
    }
    __syncthreads();
    #pragma unroll
    for (int k = 0; k < 16; k++) {
        if (bkt[k] >= 0) {
            int pos = base[bkt[k]] + atomicAdd(&cnt[bkt[k]], 1);
            outbuf[pos] = pr[k];
        }
    }
}

// ---- phase 3b: fine scatter within coarse segments ----
// Chunk of packed1 (coarse-sorted); for each overlapped coarse bin, LDS-hist its
// 64 fine buckets, reserve sub-runs (~128 edges = 512B), rewrite to gather format.
__global__ __launch_bounds__(512) void fine_scatter_kernel(
        const unsigned* __restrict__ packed1, int* __restrict__ gcursor,
        unsigned* __restrict__ packed2, const int* __restrict__ offsets,
        int NB, long long total) {
    __shared__ int cnt[64], base[64];
    __shared__ int sc_lo, sc_hi;
    const long long cs = (long long)blockIdx.x * SCHUNK;
    if (cs >= total) return;
    const long long ce = min(total, cs + (long long)SCHUNK);
    const int tid = threadIdx.x;

    if (tid == 0) {
        int c = 0;
        while ((long long)offsets[min((c + 1) << 6, NB)] <= cs) c++;
        sc_lo = c;
        while ((long long)offsets[min((c + 1) << 6, NB)] < ce) c++;
        sc_hi = c;
    }
    __syncthreads();
    const int clo = sc_lo, chi = sc_hi;

    for (int c = clo; c <= chi; c++) {
        const int fb0 = c << 6;
        const long long lo = max(cs, (long long)offsets[min(fb0, NB)]);
        const long long hi = min(ce, (long long)offsets[min(fb0 + 64, NB)]);
        if (lo >= hi) continue;
        if (tid < 64) cnt[tid] = 0;
        __syncthreads();
        for (long long i = lo + tid; i < hi; i += 512) {
            unsigned p = packed1[i];
            atomicAdd(&cnt[(p >> NPB_SHIFT) & 63], 1);
        }
        __syncthreads();
        if (tid < 64) {
            int cc = cnt[tid];
            base[tid] = cc ? atomicAdd(&gcursor[fb0 + tid], cc) : 0;
            cnt[tid] = 0;
        }
        __syncthreads();
        for (long long i = lo + tid; i < hi; i += 512) {
            unsigned p = packed1[i];
            int f = (p >> NPB_SHIFT) & 63;
            int pos = base[f] + atomicAdd(&cnt[f], 1);
            packed2[pos] = ((p >> CSHIFT) << NPB_SHIFT) | (p & (NPB - 1));
        }
        __syncthreads();
    }
}

// ---- phase 4: per-bucket counting sort by (src-tile, dstlo) TILE-MAJOR +
// tile-swept MLP4 gather (R9 accumulate, R10 single-nt-read staging). ----
__global__ __launch_bounds__(256) void bucket_gather_kernel(
        const float* __restrict__ x, const int* __restrict__ offsets,
        const unsigned* __restrict__ packed, float* __restrict__ out,
        int N, int shift, int NT) {
    extern __shared__ int lds[];
    unsigned* sorted = (unsigned*)lds;        // [CH]
    int* cnt = lds + CH;                      // [nbins] -> becomes cursor
    int* binoff = cnt + NT * NPB;             // [nbins+1]
    const int nbins = NT * NPB;

    const int b = blockIdx.x;
    const int tid = threadIdx.x;
    const int g = tid >> 4;   // group 0..15 (owns nodes 4g..4g+3)
    const int q = tid & 15;   // quad within row
    const int beg = offsets[b], end = offsets[b + 1];
    const float* xq = x + q * 4;

    float4 acc[4];
    acc[0] = acc[1] = acc[2] = acc[3] = make_float4(0.f, 0.f, 0.f, 0.f);

    for (int cs = beg; cs < end; cs += CH) {
        const int m = min(CH, end - cs);
        for (int i = tid; i < nbins; i += 256) cnt[i] = 0;
        __syncthreads();
        // hist + register stage (CH == 16*256); key = tile*NPB + dstlo
        unsigned pr[16];
        #pragma unroll
        for (int k = 0; k < 16; k++) {
            const int i = tid + (k << 8);
            if (i < m) {
                unsigned p = __builtin_nontemporal_load(packed + cs + i);
                pr[k] = p;
                int key = (int)((p >> (NPB_SHIFT + shift)) << NPB_SHIFT) | (int)(p & (NPB - 1));
                atomicAdd(&cnt[key], 1);
            }
        }
        __syncthreads();
        if (tid < 64) {  // wave 0: scan over nbins; cnt becomes exclusive cursor
            const int K = (nbins + 63) >> 6;
            const int base = tid * K;
            int S = 0;
            for (int k = 0; k < K; k++) {
                int i = base + k;
                if (i < nbins) S += cnt[i];
            }
            int inc = S;
            #pragma unroll
            for (int off = 1; off < 64; off <<= 1) {
                int t = __shfl_up(inc, off, 64);
                if (tid >= off) inc += t;
            }
            int run = inc - S;  // exclusive lane offset
            for (int k = 0; k < K; k++) {
                int i = base + k;
                if (i < nbins) {
                    int c = cnt[i];
                    cnt[i] = run;
                    binoff[i + 1] = run + c;
                    run += c;
                }
            }
            if (tid == 0) binoff[0] = 0;
        }
        __syncthreads();
        #pragma unroll
        for (int k = 0; k < 16; k++) {
            const int i = tid + (k << 8);
            if (i < m) {
                unsigned p = pr[k];
                int key = (int)((p >> (NPB_SHIFT + shift)) << NPB_SHIFT) | (int)(p & (NPB - 1));
                int pos = atomicAdd(&cnt[key], 1);
                sorted[pos] = p;
            }
        }
        __syncthreads();
        // tile-swept accumulation (R9): per tile, per node j, MLP-4 inner loop
        for (int t = 0; t < NT; t++) {
            #pragma unroll
            for (int j = 0; j < 4; j++) {
                const int dl = 4 * g + j;
                const int key = t * NPB + dl;
                const int rb = binoff[key], re = binoff[key + 1];
                int e = rb;
                for (; e + 3 < re; e += 4) {  // 4 row-gathers in flight
                    unsigned p0 = sorted[e], p1 = sorted[e + 1];
                    unsigned p2 = sorted[e + 2], p3 = sorted[e + 3];
                    const float4 v0 = *(const float4*)(xq + ((long long)(p0 >> NPB_SHIFT)) * D);
                    const float4 v1 = *(const float4*)(xq + ((long long)(p1 >> NPB_SHIFT)) * D);
                    const float4 v2 = *(const float4*)(xq + ((long long)(p2 >> NPB_SHIFT)) * D);
                    const float4 v3 = *(const float4*)(xq + ((long long)(p3 >> NPB_SHIFT)) * D);
                    acc[j].x += (v0.x + v1.x) + (v2.x + v3.x);
                    acc[j].y += (v0.y + v1.y) + (v2.y + v3.y);
                    acc[j].z += (v0.z + v1.z) + (v2.z + v3.z);
                    acc[j].w += (v0.w + v1.w) + (v2.w + v3.w);
                }
                for (; e < re; e++) {
                    unsigned p = sorted[e];
                    const float4 v = *(const float4*)(xq + ((long long)(p >> NPB_SHIFT)) * D);
                    acc[j].x += v.x; acc[j].y += v.y; acc[j].z += v.z; acc[j].w += v.w;
                }
            }
        }
        __syncthreads();  // gather reads done before next chunk reuses LDS
    }

    const int node0 = b * NPB;
    #pragma unroll
    for (int j = 0; j < 4; j++) {
        const int node = node0 + 4 * g + j;
        if (node < N)
            *(float4*)(out + (long long)node * D + q * 4) = acc[j];
    }
}

// ---- fallback: direct fp32 atomics (R1), needs no workspace ----
__global__ __launch_bounds__(256) void scatter_add_kernel(
        const float* __restrict__ x, const void* __restrict__ up_idx,
        const void* __restrict__ down_idx, float* __restrict__ out,
        const int* __restrict__ dtype_flag, int num_edges) {
    const int is64 = *dtype_flag;
    const long long total = 2LL * num_edges * Q;
    const long long stride = (long long)gridDim.x * blockDim.x;
    for (long long t = (long long)blockIdx.x * blockDim.x + threadIdx.x;
         t < total; t += stride) {
        const int quad = (int)(t & (Q - 1));
        long long eg = t >> 4;
        const void* idx = up_idx;
        if (eg >= num_edges) { idx = down_idx; eg -= num_edges; }
        int src = load_idx_nt(idx, eg, is64);
        int dst = load_idx_nt(idx, num_edges + eg, is64);
        const float4 v = *(const float4*)(x + (long long)src * D + quad * 4);
        float* o = out + (long long)dst * D + quad * 4;
        unsafeAtomicAdd(o + 0, v.x);
        unsafeAtomicAdd(o + 1, v.y);
        unsafeAtomicAdd(o + 2, v.z);
        unsafeAtomicAdd(o + 3, v.w);
    }
}

extern "C" void kernel_launch(void* const* d_in, const int* in_sizes, int n_in,
                              void* d_out, int out_size, void* d_ws, size_t ws_size,
                              hipStream_t stream) {
    const float* x = (const float*)d_in[0];
    const void* up_idx = d_in[1];
    const void* down_idx = d_in[2];
    float* out = (float*)d_out;

    const int E = in_sizes[1] / 2;   // [2, E]
    const int N = out_size / D;      // [N, 64]
    const int NB = (N + NPB - 1) / NPB;
    const int NCC = (NB + 63) >> 6;  // coarse bins (4096 nodes each)
    const long long Etot = 2LL * E;

    // src tile shift: 8192 rows (2MB) preferred; coarsen so NT <= MAXT
    int shift = 13;
    while ((((long long)(N - 1) >> shift) + 1) > MAXT) shift++;
    const int NT = (int)(((long long)(N - 1) >> shift) + 1);

    // ws layout (ints):
    // flag(64) | counts[NB] | offsets[NB+16] | cursors[NB] | ccursor[NCCpad] | packed1[Etot] | packed2[Etot]
    int* ws_i = (int*)d_ws;
    int* flag = ws_i;
    int* counts = ws_i + 64;
    int* offsets = counts + NB;
    int* cursors = offsets + NB + 16;
    int* ccursor = cursors + NB;
    const int nccpad = (NCC + 15) & ~15;
    unsigned* packed1 = (unsigned*)(ccursor + nccpad);
    unsigned* packed2 = packed1 + Etot;

    const size_t need1 = ((size_t)64 + 3LL * NB + 16 + nccpad + Etot) * 4 + 64;
    const size_t need2 = ((size_t)64 + 3LL * NB + 16 + nccpad + 2LL * Etot) * 4 + 64;
    const bool twopass = (ws_size >= need2) && (N <= (1 << 20)) && Etot < (1LL << 31);
    const bool onepass = !twopass && (ws_size >= need1) && (N <= (1 << 25)) && Etot < (1LL << 31);

    detect_idx_dtype<<<1, 64, 0, stream>>>((const int*)up_idx, flag);

    if (twopass || onepass) {
        hipMemsetAsync(counts, 0, (size_t)NB * sizeof(int), stream);
        bucket_hist_kernel<<<2048, 256, NB * sizeof(int), stream>>>(
            up_idx, down_idx, counts, flag, E, NB);
        scan_kernel<<<1, 1024, 0, stream>>>(counts, offsets, cursors, ccursor, NB, NCC);
        const int sblocks = (int)((Etot + SCHUNK - 1) / SCHUNK);
        const unsigned* gsrc;
        if (twopass) {
            radix_scatter_kernel<<<sblocks, 512, 2 * NCC * sizeof(int), stream>>>(
                up_idx, down_idx, ccursor, packed1, flag, E, CSHIFT, NCC);
            fine_scatter_kernel<<<sblocks, 512, 0, stream>>>(
                packed1, cursors, packed2, offsets, NB, Etot);
            gsrc = packed2;
        } else {
            radix_scatter_kernel<<<sblocks, 512, 2 * NB * sizeof(int), stream>>>(
                up_idx, down_idx, cursors, packed1, flag, E, NPB_SHIFT, NB);
            gsrc = packed1;
        }
        const int nbins = NT * NPB;
        const size_t glds = (size_t)(CH + 2 * nbins + 4) * 4;
        bucket_gather_kernel<<<NB, 256, glds, stream>>>(
            x, offsets, gsrc, out, N, shift, NT);
    } else {
        hipMemsetAsync(d_out, 0, (size_t)out_size * sizeof(float), stream);
        scatter_add_kernel<<<8192, 256, 0, stream>>>(x, up_idx, down_idx, out, flag, E);
    }
}